// Round 11
// baseline (197.962 us; speedup 1.0000x reference)
//
#include <hip/hip_runtime.h>
#include <hip/hip_fp16.h>

#define NN 50000     // nodes
#define NE 800000    // edges
#define NG 1024      // graphs
#define NP 16384     // pairs
#define NCL 16       // cell lines
#define INCH 64
#define EMB 128
#define HID 256

#define NB 391       // node buckets of 128 (CDIV(NN,128))
#define NCHUNK 400   // edge chunks
#define EPB 2000     // edges per chunk (NE = 400*2000 exactly)

#define CDIV(a,b) (((a)+(b)-1)/(b))

// ---------------- block exclusive scan (NW waves) ----------------
template<int NW>
__device__ __forceinline__ int block_excl_scan(int v, int t, int* incl_out) {
    int lane = t & 63, w = t >> 6;
    int s = v;
#pragma unroll
    for (int d = 1; d < 64; d <<= 1) {
        int u = __shfl_up(s, d, 64);
        if (lane >= d) s += u;
    }
    __shared__ int wsum[NW];
    if (lane == 63) wsum[w] = s;
    __syncthreads();
    int add = 0;
    for (int k = 0; k < w; ++k) add += wsum[k];
    *incl_out = s + add;
    return s + add - v;
}

// ---------------- Pass A: per-chunk bucket histogram ----------------
__global__ __launch_bounds__(256) void k_cnt(const int* __restrict__ cols,
                                             int* __restrict__ cnt) {
    __shared__ int hist[NB];
    int ch = blockIdx.x, t = threadIdx.x;
    for (int b = t; b < NB; b += 256) hist[b] = 0;
    __syncthreads();
    for (int e = ch * EPB + t; e < (ch + 1) * EPB; e += 256)
        atomicAdd(&hist[cols[e] >> 7], 1);
    __syncthreads();
    for (int b = t; b < NB; b += 256) cnt[b * NCHUNK + ch] = hist[b];
}

// ---------------- Pass B1: per-bucket scan over chunks ----------------
__global__ __launch_bounds__(512) void k_bscan(int* __restrict__ cnt,
                                               int* __restrict__ btot) {
    int b = blockIdx.x, t = threadIdx.x;
    int v = (t < NCHUNK) ? cnt[b * NCHUNK + t] : 0;
    int incl;
    int excl = block_excl_scan<8>(v, t, &incl);
    if (t < NCHUNK) cnt[b * NCHUNK + t] = excl;
    if (t == NCHUNK - 1) btot[b] = incl;
}

// ---------------- Pass B2: bucket-base scan ----------------
__global__ __launch_bounds__(512) void k_btot(const int* __restrict__ btot,
                                              int* __restrict__ bbase) {
    int t = threadIdx.x;
    int v = (t < NB) ? btot[t] : 0;
    int incl;
    int excl = block_excl_scan<8>(v, t, &incl);
    if (t < NB) bbase[t] = excl;
    if (t == NB - 1) bbase[NB] = incl;   // = NE
}

// ---------------- Pass C: partition edges (packed r<<7|c_local) ----------------
__global__ __launch_bounds__(256) void k_part(const int* __restrict__ rows,
                                              const int* __restrict__ cols,
                                              const int* __restrict__ cnt,
                                              const int* __restrict__ bbase,
                                              int* __restrict__ ebuf) {
    __shared__ int cur[NB];
    int ch = blockIdx.x, t = threadIdx.x;
    for (int b = t; b < NB; b += 256) cur[b] = bbase[b] + cnt[b * NCHUNK + ch];
    __syncthreads();
    for (int e = ch * EPB + t; e < (ch + 1) * EPB; e += 256) {
        int c = cols[e], r = rows[e];
        int pos = atomicAdd(&cur[c >> 7], 1);
        ebuf[pos] = (r << 7) | (c & 127);
    }
}

// ---------------- Pass D: per-bucket counting sort -> srows/off/dinv + x->fp16 ----------------
__global__ __launch_bounds__(256) void k_bsort(const int* __restrict__ ebuf,
                                               const int* __restrict__ bbase,
                                               const float* __restrict__ x,
                                               int* __restrict__ off,
                                               float* __restrict__ dinv,
                                               int* __restrict__ srows,
                                               __half* __restrict__ xs) {
    __shared__ int   ldeg[128];
    __shared__ int   lcur[128];
    __shared__ float ldinv[128];
    int b = blockIdx.x, t = threadIdx.x;
    int n0 = b << 7;
    int nloc = min(128, NN - n0);
    int beg = bbase[b], end = bbase[b + 1];
    if (t < 128) ldeg[t] = 0;
    __syncthreads();
    for (int i = beg + t; i < end; i += 256)
        atomicAdd(&ldeg[ebuf[i] & 127], 1);
    __syncthreads();
    int v = (t < nloc) ? ldeg[t] : 0;
    int incl;
    int excl = block_excl_scan<4>(v, t, &incl);
    if (t < nloc) {
        off[n0 + t]  = beg + excl + v;            // END offset convention
        float d = rsqrtf((float)(v + 1));         // +1 self-loop
        dinv[n0 + t] = d;
        ldinv[t] = d;
        lcur[t] = beg + excl;
    }
    __syncthreads();
    for (int i = beg + t; i < end; i += 256) {
        int e = ebuf[i];
        int pos = atomicAdd(&lcur[e & 127], 1);
        srows[pos] = e >> 7;
    }
    // fused: xs[row] = fp16(dinv[row] * x[row]) for this bucket's rows
    const float4* Xx = (const float4*)x;
#pragma unroll
    for (int i = 0; i < 8; ++i) {
        int f4 = t + i * 256;                     // 0..2047 (128 rows x 16 f4)
        int rloc = f4 >> 4, kq = f4 & 15;
        if (rloc < nloc) {
            float d = ldinv[rloc];
            float4 vv = Xx[(size_t)(n0 + rloc) * 16 + kq];
            __half2 h[2];
            h[0] = __floats2half2_rn(d * vv.x, d * vv.y);
            h[1] = __floats2half2_rn(d * vv.z, d * vv.w);
            ((float2*)xs)[(size_t)(n0 + rloc) * 16 + kq] = *(float2*)h;
        }
    }
}

// ---------------- gather on pre-scaled fp16 rows, fp16 output ----------------
// SRC' (fp16) already scaled by dinv[row]; DST[c] = fp16(dinv[c]*(sum_e SRC'[r] + SRC'[c])).
// ZB: first 512 blocks also zero zbuf[131072] (gsum) -- free fusion.
template<int FEAT, bool ZB>
__global__ __launch_bounds__(256) void k_gath_h(const int* __restrict__ off,
                                                const int* __restrict__ srows,
                                                const float* __restrict__ dinv,
                                                const __half* __restrict__ SRC,
                                                __half* __restrict__ DST,
                                                float* __restrict__ zbuf) {
    if (ZB) {
        if (blockIdx.x < 512) zbuf[(blockIdx.x << 8) + threadIdx.x] = 0.f;
    }
    constexpr int NC = FEAT / 8;    // 16B chunks (8 halfs) per row
    constexpr int PL = NC / 8;      // chunks per lane (1 for 64, 2 for 128)
    int node = blockIdx.x * 4 + (threadIdx.x >> 6);
    int lane = threadIdx.x & 63;
    int slot = lane >> 3, q = lane & 7;
    if (node >= NN) return;
    int beg = node ? off[node - 1] : 0;
    int end = off[node];
    float di = dinv[node];
    const float4* S4 = (const float4*)SRC;

    float acc[PL][8];
#pragma unroll
    for (int i = 0; i < PL; ++i)
#pragma unroll
        for (int j = 0; j < 8; ++j) acc[i][j] = 0.f;

    if (slot == 0) {
#pragma unroll
        for (int i = 0; i < PL; ++i) {
            float4 raw = S4[node * NC + i * 8 + q];
            const __half2* h = (const __half2*)&raw;
#pragma unroll
            for (int j = 0; j < 4; ++j) {
                float2 f = __half22float2(h[j]);
                acc[i][2 * j + 0] = f.x;
                acc[i][2 * j + 1] = f.y;
            }
        }
    }
    for (int e = beg + slot; e < end; e += 8) {
        int r = srows[e];
#pragma unroll
        for (int i = 0; i < PL; ++i) {
            float4 raw = S4[r * NC + i * 8 + q];
            const __half2* h = (const __half2*)&raw;
#pragma unroll
            for (int j = 0; j < 4; ++j) {
                float2 f = __half22float2(h[j]);
                acc[i][2 * j + 0] += f.x;
                acc[i][2 * j + 1] += f.y;
            }
        }
    }
#pragma unroll
    for (int d = 8; d < 64; d <<= 1)
#pragma unroll
        for (int i = 0; i < PL; ++i)
#pragma unroll
            for (int j = 0; j < 8; ++j)
                acc[i][j] += __shfl_xor(acc[i][j], d, 64);

    if (lane < 8) {
        float4* D4 = (float4*)DST;   // 8 halfs per float4
#pragma unroll
        for (int i = 0; i < PL; ++i) {
            float4 pk;
            __half2* hp = (__half2*)&pk;
            hp[0] = __floats2half2_rn(di * acc[i][0], di * acc[i][1]);
            hp[1] = __floats2half2_rn(di * acc[i][2], di * acc[i][3]);
            hp[2] = __floats2half2_rn(di * acc[i][4], di * acc[i][5]);
            hp[3] = __floats2half2_rn(di * acc[i][6], di * acc[i][7]);
            D4[node * NC + i * 8 + lane] = pk;
        }
    }
}

// ---------------- node GEMM: Y[M,128] = X[M,K](fp16) @ W[K,128](f32) + bias, relu ----------------
// 128x128 tile, 256 thr, 8x8 per thread (tr=t>>4 rows, tc=t&15 cols), kc=32.
// RS: row-scale + fp16 row-major out. POOL: run-length mean-pool atomics into Y=gsum.
template<int K, bool RS, bool POOL>
__global__ __launch_bounds__(256) void gemm128(const __half* __restrict__ X,
                                               const float* __restrict__ W,
                                               const float* __restrict__ bias,
                                               const float* __restrict__ rs,
                                               const int* __restrict__ batch,
                                               float* __restrict__ Y, int M) {
    __shared__ float Xt[32][132];   // [k][row]; stride 132 -> stage writes 2-way only
    __shared__ float Wsh[32][128];  // [k][col]
    __shared__ int sb[128];
    const int t  = threadIdx.x;
    const int tr = t >> 4;          // rows 8tr..8tr+7
    const int tc = t & 15;          // cols 8tc..8tc+7
    const int row0 = blockIdx.x * 128;
    const int lrow = t & 127;       // staging row
    const int khalf = t >> 7;       // staging k-half (16 k each)

    if (POOL && t < 128) sb[t] = (row0 + t < M) ? batch[row0 + t] : -1;

    float acc[8][8];
#pragma unroll
    for (int i = 0; i < 8; ++i)
#pragma unroll
        for (int j = 0; j < 8; ++j) acc[i][j] = 0.f;

    const float4* W4 = (const float4*)W;
    float4* Ws4 = (float4*)&Wsh[0][0];
    const float4* X8 = (const float4*)X;   // 8 halfs per float4

    for (int k0 = 0; k0 < K; k0 += 32) {
        __syncthreads();
        // X stage: thread (lrow, khalf) covers k [k0+16*khalf, +16) of its row.
        {
            int gr = row0 + lrow;
            float4 ra = make_float4(0.f, 0.f, 0.f, 0.f), rb = ra;
            if (gr < M) {
                size_t base = ((size_t)gr * K + k0 + 16 * khalf) >> 3;
                ra = X8[base];
                rb = X8[base + 1];
            }
            const __half2* ha = (const __half2*)&ra;
            const __half2* hb = (const __half2*)&rb;
            int kb = 16 * khalf;
#pragma unroll
            for (int j = 0; j < 4; ++j) {
                float2 f = __half22float2(ha[j]);
                Xt[kb + 2 * j + 0][lrow] = f.x;
                Xt[kb + 2 * j + 1][lrow] = f.y;
            }
#pragma unroll
            for (int j = 0; j < 4; ++j) {
                float2 f = __half22float2(hb[j]);
                Xt[kb + 8 + 2 * j + 0][lrow] = f.x;
                Xt[kb + 8 + 2 * j + 1][lrow] = f.y;
            }
        }
        // W stage: 32k x 128 cols = 1024 float4s, coalesced
#pragma unroll
        for (int i = 0; i < 4; ++i) {
            int f4 = t + i * 256;
            Ws4[f4] = W4[(k0 + (f4 >> 5)) * 32 + (f4 & 31)];
        }
        __syncthreads();
#pragma unroll 2
        for (int k = 0; k < 32; ++k) {
            float xf[8], wf[8];
            *(float4*)&xf[0] = *(const float4*)&Xt[k][8 * tr];
            *(float4*)&xf[4] = *(const float4*)&Xt[k][8 * tr + 4];
            *(float4*)&wf[0] = *(const float4*)&Wsh[k][8 * tc];
            *(float4*)&wf[4] = *(const float4*)&Wsh[k][8 * tc + 4];
#pragma unroll
            for (int i = 0; i < 8; ++i)
#pragma unroll
                for (int j = 0; j < 8; ++j)
                    acc[i][j] = fmaf(xf[i], wf[j], acc[i][j]);
        }
    }

    float b[8];
    *(float4*)&b[0] = ((const float4*)bias)[2 * tc + 0];
    *(float4*)&b[4] = ((const float4*)bias)[2 * tc + 1];

    if (POOL) {
        int rung = -1;
        float run[8];
#pragma unroll
        for (int j = 0; j < 8; ++j) run[j] = 0.f;
#pragma unroll
        for (int i = 0; i < 8; ++i) {
            int gr = row0 + 8 * tr + i;
            int g = (gr < M) ? sb[8 * tr + i] : -1;
            if (g != rung) {
                if (rung >= 0) {
                    float* dst = &Y[rung * 128 + 8 * tc];
#pragma unroll
                    for (int j = 0; j < 8; ++j) atomicAdd(dst + j, run[j]);
                }
#pragma unroll
                for (int j = 0; j < 8; ++j) run[j] = 0.f;
                rung = g;
            }
            if (g >= 0) {
#pragma unroll
                for (int j = 0; j < 8; ++j)
                    run[j] += fmaxf(acc[i][j] + b[j], 0.f);
            }
        }
        if (rung >= 0) {
            float* dst = &Y[rung * 128 + 8 * tc];
#pragma unroll
            for (int j = 0; j < 8; ++j) atomicAdd(dst + j, run[j]);
        }
        return;
    }

    // normal epilogue: fp16 row-major out (optionally row-scaled)
    __half* Yh = (__half*)Y;
#pragma unroll
    for (int i = 0; i < 8; ++i) {
        int gr = row0 + 8 * tr + i;
        if (gr < M) {
            float d = RS ? rs[gr] : 1.f;
            float4 pk;
            __half2* hp = (__half2*)&pk;
#pragma unroll
            for (int j = 0; j < 4; ++j)
                hp[j] = __floats2half2_rn(d * fmaxf(acc[i][2 * j] + b[2 * j], 0.f),
                                          d * fmaxf(acc[i][2 * j + 1] + b[2 * j + 1], 0.f));
            ((float4*)Yh)[((size_t)gr * 128 + 8 * tc) >> 3] = pk;
        }
    }
}

// ---------------- normalize gsum -> mean (counts via binary search) ----------------
__global__ __launch_bounds__(128) void k_div(float* __restrict__ gsum,
                                             const int* __restrict__ batch) {
    int g = blockIdx.x;
    __shared__ float inv;
    if (threadIdx.x == 0) {
        int lo = 0, hi = NN;
        while (lo < hi) { int m = (lo + hi) >> 1; if (batch[m] < g) lo = m + 1; else hi = m; }
        int s = lo;
        lo = 0; hi = NN;
        while (lo < hi) { int m = (lo + hi) >> 1; if (batch[m] < g + 1) lo = m + 1; else hi = m; }
        float c = (float)(lo - s);
        inv = 1.f / fmaxf(c, 1.f);
    }
    __syncthreads();
    gsum[g * 128 + threadIdx.x] *= inv;
}

// ---------------- batched GEMM: {A,B}arr[c][g][t] = GE @ W1-half (128x128 tile) ----------------
__global__ __launch_bounds__(256) void gemm_bat(const float* __restrict__ GE,
                                                const float* __restrict__ W1,
                                                float* __restrict__ Aarr,
                                                float* __restrict__ Barr) {
    __shared__ float Xt[32][132];
    __shared__ float Wsh[32][128];
    const int t  = threadIdx.x;
    const int tr = t >> 4;
    const int tc = t & 15;
    const int row0 = blockIdx.x * 128;
    const int y = blockIdx.y;
    const int z = blockIdx.z;
    const int lrow = t & 127;       // staging row
    const int khalf = t >> 7;       // staging: f4s 4*khalf..4*khalf+3

    const float* Wbase = W1 + (z >> 1) * (HID * HID) + (z & 1) * (128 * HID) + y * 128;

    float acc[8][8];
#pragma unroll
    for (int i = 0; i < 8; ++i)
#pragma unroll
        for (int j = 0; j < 8; ++j) acc[i][j] = 0.f;

    const float4* X4 = (const float4*)GE;

    for (int k0 = 0; k0 < 128; k0 += 32) {
        __syncthreads();
        // X stage: thread (lrow,khalf): 4 float4s of its row -> 2-way-only writes
#pragma unroll
        for (int q = 0; q < 4; ++q) {
            int kq = 4 * khalf + q;
            float4 xv = X4[(row0 + lrow) * 32 + (k0 >> 2) + kq];
            Xt[4 * kq + 0][lrow] = xv.x;
            Xt[4 * kq + 1][lrow] = xv.y;
            Xt[4 * kq + 2][lrow] = xv.z;
            Xt[4 * kq + 3][lrow] = xv.w;
        }
        const float4* Wc4 = (const float4*)(Wbase + k0 * HID);
#pragma unroll
        for (int i = 0; i < 4; ++i) {
            int f4 = t + i * 256;
            int k = f4 >> 5, c4 = f4 & 31;
            ((float4*)&Wsh[k][0])[c4] = Wc4[k * 64 + c4];
        }
        __syncthreads();
#pragma unroll 2
        for (int k = 0; k < 32; ++k) {
            float xf[8], wf[8];
            *(float4*)&xf[0] = *(const float4*)&Xt[k][8 * tr];
            *(float4*)&xf[4] = *(const float4*)&Xt[k][8 * tr + 4];
            *(float4*)&wf[0] = *(const float4*)&Wsh[k][8 * tc];
            *(float4*)&wf[4] = *(const float4*)&Wsh[k][8 * tc + 4];
#pragma unroll
            for (int i = 0; i < 8; ++i)
#pragma unroll
                for (int j = 0; j < 8; ++j)
                    acc[i][j] = fmaf(xf[i], wf[j], acc[i][j]);
        }
    }
    float* Obase = (z & 1) ? Barr : Aarr;
    float4* O4 = (float4*)Obase;
#pragma unroll
    for (int i = 0; i < 8; ++i) {
        int g = row0 + 8 * tr + i;
        size_t base = ((size_t)((z >> 1) * NG + g) * HID + y * 128 + 8 * tc) >> 2;
        O4[base + 0] = make_float4(acc[i][0], acc[i][1], acc[i][2], acc[i][3]);
        O4[base + 1] = make_float4(acc[i][4], acc[i][5], acc[i][6], acc[i][7]);
    }
}

// ---------------- pair epilogue ----------------
__global__ __launch_bounds__(256) void k_pair(const float* __restrict__ Aarr,
                                              const float* __restrict__ Barr,
                                              const int* __restrict__ ddb,
                                              const int* __restrict__ ecl,
                                              const float* __restrict__ B1,
                                              const float* __restrict__ W2,
                                              const float* __restrict__ B2,
                                              float* __restrict__ out) {
    int p = blockIdx.x * 4 + (threadIdx.x >> 6);
    int lane = threadIdx.x & 63;
    int c = ecl[p];
    int a = ddb[p];
    int b = ddb[NP + p];
    const float4* rA = (const float4*)&Aarr[((size_t)c * NG + a) * HID];
    const float4* rB = (const float4*)&Barr[((size_t)c * NG + b) * HID];
    const float4* b1 = (const float4*)&B1[c * HID];
    const float4* w2 = (const float4*)&W2[c * HID];
    float4 va = rA[lane], vb = rB[lane], v1 = b1[lane], v2 = w2[lane];
    float hx = va.x + vb.x + v1.x;
    float hy = va.y + vb.y + v1.y;
    float hz = va.z + vb.z + v1.z;
    float hw = va.w + vb.w + v1.w;
    float s = 0.f;
    s = fmaf(hx > 0.f ? hx : 0.f, v2.x, s);
    s = fmaf(hy > 0.f ? hy : 0.f, v2.y, s);
    s = fmaf(hz > 0.f ? hz : 0.f, v2.z, s);
    s = fmaf(hw > 0.f ? hw : 0.f, v2.w, s);
    for (int o = 32; o; o >>= 1) s += __shfl_down(s, o, 64);
    if (lane == 0) out[p] = s + B2[c];
}

// ---------------- launch ----------------
extern "C" void kernel_launch(void* const* d_in, const int* in_sizes, int n_in,
                              void* d_out, int out_size, void* d_ws, size_t ws_size,
                              hipStream_t stream) {
    const float* x    = (const float*)d_in[0];
    const float* c1w  = (const float*)d_in[1];
    const float* c1b  = (const float*)d_in[2];
    const float* c2w  = (const float*)d_in[3];
    const float* c2b  = (const float*)d_in[4];
    const float* rw1  = (const float*)d_in[5];
    const float* rb1  = (const float*)d_in[6];
    const float* rw2  = (const float*)d_in[7];
    const float* rb2  = (const float*)d_in[8];
    const int*   eidx = (const int*)d_in[9];    // [2, NE]: rows then cols
    const int*   batch= (const int*)d_in[10];
    const int*   ddb  = (const int*)d_in[11];   // [2, NP]
    const int*   ecl  = (const int*)d_in[12];
    float* out = (float*)d_out;

    // ---- workspace layout (floats) ----
    // off(50048) | srows(NE) | dinv(50048) | bufA(6.4M) | bufB(6.4M)
    // temporal aliases:
    //   ebuf  (int NE)         -> bufA[0..0.8M)      (k_part .. k_bsort)
    //   cnt/btot/bbase         -> bufB[1.7M..1.86M)  (k_cnt .. k_bsort)
    //   xs    (fp16 [NN][64])  -> bufB[0..1.6M)      (k_bsort .. gath1)
    //   aggXh (fp16 [NN][64])  -> bufA[0..1.6M)      (gath1 .. gemm1)
    //   H1h   (fp16 [NN][128]) -> bufB[0..3.2M)      (gemm1 .. gath2)
    //   aggHh (fp16 [NN][128]) -> bufA[0..3.2M)      (gath2 .. gemm2)
    //   gsum  (f32 131072)     -> bufA[4.5M..4.63M)  (zeroed in gath1; gemm2 .. gemm_bat)
    //   Aarr  (f32 4.19M)      -> bufA[0..4.19M)     (gemm_bat .. k_pair)
    //   Barr  (f32 4.19M)      -> bufB[0..4.19M)     (gemm_bat .. k_pair)
    int*   off   = (int*)d_ws;
    int*   srows = off + 50048;
    float* dinv  = (float*)(srows + NE);
    float* bufA  = dinv + 50048;
    float* bufB  = bufA + NN * EMB;

    int*    ebuf  = (int*)bufA;
    int*    cnt   = (int*)(bufB + 1700000);
    int*    btot  = cnt + NB * NCHUNK;
    int*    bbase = btot + 512;
    __half* xs    = (__half*)bufB;
    __half* aggXh = (__half*)bufA;
    __half* H1h   = (__half*)bufB;
    __half* aggHh = (__half*)bufA;
    float*  gsum  = bufA + 4500000;
    float*  Aarr  = bufA;
    float*  Barr  = bufB;

    const int* erow = eidx;
    const int* ecol = eidx + NE;

    // ---- CSR build (bucketed, LDS-atomic only) + fused x->fp16 prescale ----
    k_cnt  <<<NCHUNK, 256, 0, stream>>>(ecol, cnt);
    k_bscan<<<NB,     512, 0, stream>>>(cnt, btot);
    k_btot <<<1,      512, 0, stream>>>(btot, bbase);
    k_part <<<NCHUNK, 256, 0, stream>>>(erow, ecol, cnt, bbase, ebuf);
    k_bsort<<<NB,     256, 0, stream>>>(ebuf, bbase, x, off, dinv, srows, xs);

    // ---- layer 1: aggX(fp16) = gather(xs) [+ zero gsum] ; H1'(fp16) = dinv*relu(aggX@W1+b1) ----
    k_gath_h<INCH,true><<<CDIV(NN,4),256,0,stream>>>(off, srows, dinv, xs, aggXh, gsum);
    gemm128<INCH,true,false><<<CDIV(NN,128),256,0,stream>>>(aggXh, c1w, c1b, dinv, nullptr, (float*)H1h, NN);

    // ---- layer 2: aggH(fp16) = gather(H1') ; gemm2 + fused mean-pool atomics ----
    k_gath_h<EMB,false><<<CDIV(NN,4),256,0,stream>>>(off, srows, dinv, H1h, aggHh, nullptr);
    gemm128<EMB,false,true><<<CDIV(NN,128),256,0,stream>>>(aggHh, c2w, c2b, nullptr, batch, gsum, NN);
    k_div<<<NG,128,0,stream>>>(gsum, batch);

    // ---- regressor: {A,B} = GE @ W1 halves for all 16 lines, then pair epilogue ----
    dim3 bgrid(NG/128, 2, 2*NCL);
    gemm_bat<<<bgrid,256,0,stream>>>(gsum, rw1, Aarr, Barr);
    k_pair<<<NP/4,256,0,stream>>>(Aarr, Barr, ddb, ecl, rb1, rw2, rb2, out);
}

// Round 12
// 178.305 us; speedup vs baseline: 1.1102x; 1.1102x over previous
//
#include <hip/hip_runtime.h>
#include <hip/hip_fp16.h>

#define NN 50000     // nodes
#define NE 800000    // edges
#define NG 1024      // graphs
#define NP 16384     // pairs
#define NCL 16       // cell lines
#define INCH 64
#define EMB 128
#define HID 256

#define NB 391       // node buckets of 128 (CDIV(NN,128))
#define NCHUNK 400   // edge chunks
#define EPB 2000     // edges per chunk (NE = 400*2000 exactly)

#define CDIV(a,b) (((a)+(b)-1)/(b))

typedef _Float16 f16x8 __attribute__((ext_vector_type(8)));
typedef float    f32x4 __attribute__((ext_vector_type(4)));

// ---------------- block exclusive scan (NW waves) ----------------
template<int NW>
__device__ __forceinline__ int block_excl_scan(int v, int t, int* incl_out) {
    int lane = t & 63, w = t >> 6;
    int s = v;
#pragma unroll
    for (int d = 1; d < 64; d <<= 1) {
        int u = __shfl_up(s, d, 64);
        if (lane >= d) s += u;
    }
    __shared__ int wsum[NW];
    if (lane == 63) wsum[w] = s;
    __syncthreads();
    int add = 0;
    for (int k = 0; k < w; ++k) add += wsum[k];
    *incl_out = s + add;
    return s + add - v;
}

// ---------------- Pass A: per-chunk bucket histogram ----------------
__global__ __launch_bounds__(256) void k_cnt(const int* __restrict__ cols,
                                             int* __restrict__ cnt) {
    __shared__ int hist[NB];
    int ch = blockIdx.x, t = threadIdx.x;
    for (int b = t; b < NB; b += 256) hist[b] = 0;
    __syncthreads();
    for (int e = ch * EPB + t; e < (ch + 1) * EPB; e += 256)
        atomicAdd(&hist[cols[e] >> 7], 1);
    __syncthreads();
    for (int b = t; b < NB; b += 256) cnt[b * NCHUNK + ch] = hist[b];
}

// ---------------- Pass B1: per-bucket scan over chunks ----------------
__global__ __launch_bounds__(512) void k_bscan(int* __restrict__ cnt,
                                               int* __restrict__ btot) {
    int b = blockIdx.x, t = threadIdx.x;
    int v = (t < NCHUNK) ? cnt[b * NCHUNK + t] : 0;
    int incl;
    int excl = block_excl_scan<8>(v, t, &incl);
    if (t < NCHUNK) cnt[b * NCHUNK + t] = excl;
    if (t == NCHUNK - 1) btot[b] = incl;
}

// ---------------- Pass B2: bucket-base scan ----------------
__global__ __launch_bounds__(512) void k_btot(const int* __restrict__ btot,
                                              int* __restrict__ bbase) {
    int t = threadIdx.x;
    int v = (t < NB) ? btot[t] : 0;
    int incl;
    int excl = block_excl_scan<8>(v, t, &incl);
    if (t < NB) bbase[t] = excl;
    if (t == NB - 1) bbase[NB] = incl;   // = NE
}

// ---------------- Pass C: partition edges (packed r<<7|c_local) ----------------
__global__ __launch_bounds__(256) void k_part(const int* __restrict__ rows,
                                              const int* __restrict__ cols,
                                              const int* __restrict__ cnt,
                                              const int* __restrict__ bbase,
                                              int* __restrict__ ebuf) {
    __shared__ int cur[NB];
    int ch = blockIdx.x, t = threadIdx.x;
    for (int b = t; b < NB; b += 256) cur[b] = bbase[b] + cnt[b * NCHUNK + ch];
    __syncthreads();
    for (int e = ch * EPB + t; e < (ch + 1) * EPB; e += 256) {
        int c = cols[e], r = rows[e];
        int pos = atomicAdd(&cur[c >> 7], 1);
        ebuf[pos] = (r << 7) | (c & 127);
    }
}

// ---------------- Pass D: per-bucket counting sort -> srows/off/dinv + x->fp16 ----------------
__global__ __launch_bounds__(256) void k_bsort(const int* __restrict__ ebuf,
                                               const int* __restrict__ bbase,
                                               const float* __restrict__ x,
                                               int* __restrict__ off,
                                               float* __restrict__ dinv,
                                               int* __restrict__ srows,
                                               __half* __restrict__ xs) {
    __shared__ int   ldeg[128];
    __shared__ int   lcur[128];
    __shared__ float ldinv[128];
    int b = blockIdx.x, t = threadIdx.x;
    int n0 = b << 7;
    int nloc = min(128, NN - n0);
    int beg = bbase[b], end = bbase[b + 1];
    if (t < 128) ldeg[t] = 0;
    __syncthreads();
    for (int i = beg + t; i < end; i += 256)
        atomicAdd(&ldeg[ebuf[i] & 127], 1);
    __syncthreads();
    int v = (t < nloc) ? ldeg[t] : 0;
    int incl;
    int excl = block_excl_scan<4>(v, t, &incl);
    if (t < nloc) {
        off[n0 + t]  = beg + excl + v;            // END offset convention
        float d = rsqrtf((float)(v + 1));         // +1 self-loop
        dinv[n0 + t] = d;
        ldinv[t] = d;
        lcur[t] = beg + excl;
    }
    __syncthreads();
    for (int i = beg + t; i < end; i += 256) {
        int e = ebuf[i];
        int pos = atomicAdd(&lcur[e & 127], 1);
        srows[pos] = e >> 7;
    }
    // fused: xs[row] = fp16(dinv[row] * x[row]) for this bucket's rows
    const float4* Xx = (const float4*)x;
#pragma unroll
    for (int i = 0; i < 8; ++i) {
        int f4 = t + i * 256;                     // 0..2047 (128 rows x 16 f4)
        int rloc = f4 >> 4, kq = f4 & 15;
        if (rloc < nloc) {
            float d = ldinv[rloc];
            float4 vv = Xx[(size_t)(n0 + rloc) * 16 + kq];
            __half2 h[2];
            h[0] = __floats2half2_rn(d * vv.x, d * vv.y);
            h[1] = __floats2half2_rn(d * vv.z, d * vv.w);
            ((float2*)xs)[(size_t)(n0 + rloc) * 16 + kq] = *(float2*)h;
        }
    }
}

// ---------------- weight convert: WT[n][k] = fp16(W[k][n]) ----------------
__global__ __launch_bounds__(256) void k_wconv(const float* __restrict__ W,
                                               __half* __restrict__ WT, int K) {
    int i = blockIdx.x * 256 + threadIdx.x;   // over K*128, coalesced read
    if (i >= K * 128) return;
    int k = i >> 7, n = i & 127;
    WT[n * K + k] = __float2half(W[i]);
}

// ---------------- gather on pre-scaled fp16 rows, fp16 output ----------------
// SRC' (fp16) already scaled by dinv[row]; DST[c] = fp16(dinv[c]*(sum_e SRC'[r] + SRC'[c])).
// ZB: first 512 blocks also zero zbuf[131072] (gsum) -- free fusion.
template<int FEAT, bool ZB>
__global__ __launch_bounds__(256) void k_gath_h(const int* __restrict__ off,
                                                const int* __restrict__ srows,
                                                const float* __restrict__ dinv,
                                                const __half* __restrict__ SRC,
                                                __half* __restrict__ DST,
                                                float* __restrict__ zbuf) {
    if (ZB) {
        if (blockIdx.x < 512) zbuf[(blockIdx.x << 8) + threadIdx.x] = 0.f;
    }
    constexpr int NC = FEAT / 8;    // 16B chunks (8 halfs) per row
    constexpr int PL = NC / 8;      // chunks per lane (1 for 64, 2 for 128)
    int node = blockIdx.x * 4 + (threadIdx.x >> 6);
    int lane = threadIdx.x & 63;
    int slot = lane >> 3, q = lane & 7;
    if (node >= NN) return;
    int beg = node ? off[node - 1] : 0;
    int end = off[node];
    float di = dinv[node];
    const float4* S4 = (const float4*)SRC;

    float acc[PL][8];
#pragma unroll
    for (int i = 0; i < PL; ++i)
#pragma unroll
        for (int j = 0; j < 8; ++j) acc[i][j] = 0.f;

    if (slot == 0) {
#pragma unroll
        for (int i = 0; i < PL; ++i) {
            float4 raw = S4[node * NC + i * 8 + q];
            const __half2* h = (const __half2*)&raw;
#pragma unroll
            for (int j = 0; j < 4; ++j) {
                float2 f = __half22float2(h[j]);
                acc[i][2 * j + 0] = f.x;
                acc[i][2 * j + 1] = f.y;
            }
        }
    }
    for (int e = beg + slot; e < end; e += 8) {
        int r = srows[e];
#pragma unroll
        for (int i = 0; i < PL; ++i) {
            float4 raw = S4[r * NC + i * 8 + q];
            const __half2* h = (const __half2*)&raw;
#pragma unroll
            for (int j = 0; j < 4; ++j) {
                float2 f = __half22float2(h[j]);
                acc[i][2 * j + 0] += f.x;
                acc[i][2 * j + 1] += f.y;
            }
        }
    }
#pragma unroll
    for (int d = 8; d < 64; d <<= 1)
#pragma unroll
        for (int i = 0; i < PL; ++i)
#pragma unroll
            for (int j = 0; j < 8; ++j)
                acc[i][j] += __shfl_xor(acc[i][j], d, 64);

    if (lane < 8) {
        float4* D4 = (float4*)DST;   // 8 halfs per float4
#pragma unroll
        for (int i = 0; i < PL; ++i) {
            float4 pk;
            __half2* hp = (__half2*)&pk;
            hp[0] = __floats2half2_rn(di * acc[i][0], di * acc[i][1]);
            hp[1] = __floats2half2_rn(di * acc[i][2], di * acc[i][3]);
            hp[2] = __floats2half2_rn(di * acc[i][4], di * acc[i][5]);
            hp[3] = __floats2half2_rn(di * acc[i][6], di * acc[i][7]);
            D4[node * NC + i * 8 + lane] = pk;
        }
    }
}

// ---------------- MFMA node GEMM: Y[M,128] = X[M,K](fp16) @ W + bias, relu ----------------
// Block: 64 rows x 128 cols, 4 waves; wave w owns rows 16w..16w+15, loops 8 col-tiles.
// WT is the transposed fp16 weight [128 n][K k]. One LDS stage, no k-loop barriers.
// Frag layouts (m89-verified family): A lane l -> (m=l&15, k=8*(l>>4)+j);
// B lane l -> (n=l&15, k=8*(l>>4)+j); D lane l -> (col=l&15, row=4*(l>>4)+reg).
// RS: multiply rows by rs[] and emit fp16 row-major. POOL: run-length mean-pool
// atomics into Y=gsum by sorted batch.
template<int K, bool RS, bool POOL>
__global__ __launch_bounds__(256) void gemm_mf(const __half* __restrict__ X,
                                               const __half* __restrict__ WT,
                                               const float* __restrict__ bias,
                                               const float* __restrict__ rs,
                                               const int* __restrict__ batch,
                                               float* __restrict__ Y, int M) {
    constexpr int KP = K + 8;                 // padded fp16 row stride (16B-aligned)
    __shared__ __half Xs[64 * KP];
    __shared__ __half Ws[128 * KP];
    __shared__ int sb[64];
    const int t = threadIdx.x;
    const int row0 = blockIdx.x * 64;

    // stage X tile (64 x K fp16), b128 chunks, conflict-free
    const float4* X8 = (const float4*)X;
#pragma unroll
    for (int i = t; i < 64 * (K / 8); i += 256) {
        int r = i / (K / 8), ch = i % (K / 8);
        float4 v = make_float4(0.f, 0.f, 0.f, 0.f);
        if (row0 + r < M) v = X8[(size_t)(row0 + r) * (K / 8) + ch];
        *(float4*)&Xs[r * KP + ch * 8] = v;
    }
    // stage WT (128 x K fp16)
    const float4* W8 = (const float4*)WT;
#pragma unroll
    for (int i = t; i < 128 * (K / 8); i += 256) {
        int n = i / (K / 8), ch = i % (K / 8);
        *(float4*)&Ws[n * KP + ch * 8] = W8[i];
    }
    if (POOL) {
        if (t < 64) sb[t] = (row0 + t < M) ? batch[row0 + t] : -1;
    }
    __syncthreads();

    const int w  = t >> 6;
    const int l  = t & 63;
    const int lm = l & 15, lg = l >> 4;

    f32x4 acc[8];
#pragma unroll
    for (int c = 0; c < 8; ++c) acc[c] = (f32x4){0.f, 0.f, 0.f, 0.f};

#pragma unroll
    for (int kk = 0; kk < K / 32; ++kk) {
        f16x8 a = *(const f16x8*)&Xs[(16 * w + lm) * KP + kk * 32 + lg * 8];
#pragma unroll
        for (int c = 0; c < 8; ++c) {
            f16x8 bf = *(const f16x8*)&Ws[(16 * c + lm) * KP + kk * 32 + lg * 8];
            acc[c] = __builtin_amdgcn_mfma_f32_16x16x32_f16(a, bf, acc[c], 0, 0, 0);
        }
    }

    float bcol[8];
#pragma unroll
    for (int c = 0; c < 8; ++c) bcol[c] = bias[16 * c + lm];

    if (POOL) {
        // lane owns 4 consecutive rows (16w + 4lg + j) at 8 cols (16c + lm)
#pragma unroll
        for (int c = 0; c < 8; ++c) {
            int rung = -1;
            float run = 0.f;
#pragma unroll
            for (int j = 0; j < 4; ++j) {
                int rr = 16 * w + 4 * lg + j;
                int g = (row0 + rr < M) ? sb[rr] : -1;
                if (g != rung) {
                    if (rung >= 0) atomicAdd(&Y[rung * 128 + 16 * c + lm], run);
                    run = 0.f;
                    rung = g;
                }
                if (g >= 0) run += fmaxf(acc[c][j] + bcol[c], 0.f);
            }
            if (rung >= 0) atomicAdd(&Y[rung * 128 + 16 * c + lm], run);
        }
        return;
    }

    __half* Yh = (__half*)Y;
#pragma unroll
    for (int j = 0; j < 4; ++j) {
        int r = row0 + 16 * w + 4 * lg + j;
        if (r < M) {
            float d = RS ? rs[r] : 1.f;
#pragma unroll
            for (int c = 0; c < 8; ++c) {
                float v = d * fmaxf(acc[c][j] + bcol[c], 0.f);
                Yh[(size_t)r * 128 + 16 * c + lm] = __float2half(v);
            }
        }
    }
}

// ---------------- normalize gsum -> mean (counts via binary search) ----------------
__global__ __launch_bounds__(128) void k_div(float* __restrict__ gsum,
                                             const int* __restrict__ batch) {
    int g = blockIdx.x;
    __shared__ float inv;
    if (threadIdx.x == 0) {
        int lo = 0, hi = NN;
        while (lo < hi) { int m = (lo + hi) >> 1; if (batch[m] < g) lo = m + 1; else hi = m; }
        int s = lo;
        lo = 0; hi = NN;
        while (lo < hi) { int m = (lo + hi) >> 1; if (batch[m] < g + 1) lo = m + 1; else hi = m; }
        float c = (float)(lo - s);
        inv = 1.f / fmaxf(c, 1.f);
    }
    __syncthreads();
    gsum[g * 128 + threadIdx.x] *= inv;
}

// ---------------- batched GEMM: {A,B}arr[c][g][t] = GE @ W1-half (128x128 tile) ----------------
__global__ __launch_bounds__(256) void gemm_bat(const float* __restrict__ GE,
                                                const float* __restrict__ W1,
                                                float* __restrict__ Aarr,
                                                float* __restrict__ Barr) {
    __shared__ float Xt[32][132];
    __shared__ float Wsh[32][128];
    const int t  = threadIdx.x;
    const int tr = t >> 4;
    const int tc = t & 15;
    const int row0 = blockIdx.x * 128;
    const int y = blockIdx.y;
    const int z = blockIdx.z;
    const int lrow = t & 127;       // staging row
    const int khalf = t >> 7;       // staging: f4s 4*khalf..4*khalf+3

    const float* Wbase = W1 + (z >> 1) * (HID * HID) + (z & 1) * (128 * HID) + y * 128;

    float acc[8][8];
#pragma unroll
    for (int i = 0; i < 8; ++i)
#pragma unroll
        for (int j = 0; j < 8; ++j) acc[i][j] = 0.f;

    const float4* X4 = (const float4*)GE;

    for (int k0 = 0; k0 < 128; k0 += 32) {
        __syncthreads();
#pragma unroll
        for (int q = 0; q < 4; ++q) {
            int kq = 4 * khalf + q;
            float4 xv = X4[(row0 + lrow) * 32 + (k0 >> 2) + kq];
            Xt[4 * kq + 0][lrow] = xv.x;
            Xt[4 * kq + 1][lrow] = xv.y;
            Xt[4 * kq + 2][lrow] = xv.z;
            Xt[4 * kq + 3][lrow] = xv.w;
        }
        const float4* Wc4 = (const float4*)(Wbase + k0 * HID);
#pragma unroll
        for (int i = 0; i < 4; ++i) {
            int f4 = t + i * 256;
            int k = f4 >> 5, c4 = f4 & 31;
            ((float4*)&Wsh[k][0])[c4] = Wc4[k * 64 + c4];
        }
        __syncthreads();
#pragma unroll 2
        for (int k = 0; k < 32; ++k) {
            float xf[8], wf[8];
            *(float4*)&xf[0] = *(const float4*)&Xt[k][8 * tr];
            *(float4*)&xf[4] = *(const float4*)&Xt[k][8 * tr + 4];
            *(float4*)&wf[0] = *(const float4*)&Wsh[k][8 * tc];
            *(float4*)&wf[4] = *(const float4*)&Wsh[k][8 * tc + 4];
#pragma unroll
            for (int i = 0; i < 8; ++i)
#pragma unroll
                for (int j = 0; j < 8; ++j)
                    acc[i][j] = fmaf(xf[i], wf[j], acc[i][j]);
        }
    }
    float* Obase = (z & 1) ? Barr : Aarr;
    float4* O4 = (float4*)Obase;
#pragma unroll
    for (int i = 0; i < 8; ++i) {
        int g = row0 + 8 * tr + i;
        size_t base = ((size_t)((z >> 1) * NG + g) * HID + y * 128 + 8 * tc) >> 2;
        O4[base + 0] = make_float4(acc[i][0], acc[i][1], acc[i][2], acc[i][3]);
        O4[base + 1] = make_float4(acc[i][4], acc[i][5], acc[i][6], acc[i][7]);
    }
}

// ---------------- pair epilogue ----------------
__global__ __launch_bounds__(256) void k_pair(const float* __restrict__ Aarr,
                                              const float* __restrict__ Barr,
                                              const int* __restrict__ ddb,
                                              const int* __restrict__ ecl,
                                              const float* __restrict__ B1,
                                              const float* __restrict__ W2,
                                              const float* __restrict__ B2,
                                              float* __restrict__ out) {
    int p = blockIdx.x * 4 + (threadIdx.x >> 6);
    int lane = threadIdx.x & 63;
    int c = ecl[p];
    int a = ddb[p];
    int b = ddb[NP + p];
    const float4* rA = (const float4*)&Aarr[((size_t)c * NG + a) * HID];
    const float4* rB = (const float4*)&Barr[((size_t)c * NG + b) * HID];
    const float4* b1 = (const float4*)&B1[c * HID];
    const float4* w2 = (const float4*)&W2[c * HID];
    float4 va = rA[lane], vb = rB[lane], v1 = b1[lane], v2 = w2[lane];
    float hx = va.x + vb.x + v1.x;
    float hy = va.y + vb.y + v1.y;
    float hz = va.z + vb.z + v1.z;
    float hw = va.w + vb.w + v1.w;
    float s = 0.f;
    s = fmaf(hx > 0.f ? hx : 0.f, v2.x, s);
    s = fmaf(hy > 0.f ? hy : 0.f, v2.y, s);
    s = fmaf(hz > 0.f ? hz : 0.f, v2.z, s);
    s = fmaf(hw > 0.f ? hw : 0.f, v2.w, s);
    for (int o = 32; o; o >>= 1) s += __shfl_down(s, o, 64);
    if (lane == 0) out[p] = s + B2[c];
}

// ---------------- launch ----------------
extern "C" void kernel_launch(void* const* d_in, const int* in_sizes, int n_in,
                              void* d_out, int out_size, void* d_ws, size_t ws_size,
                              hipStream_t stream) {
    const float* x    = (const float*)d_in[0];
    const float* c1w  = (const float*)d_in[1];
    const float* c1b  = (const float*)d_in[2];
    const float* c2w  = (const float*)d_in[3];
    const float* c2b  = (const float*)d_in[4];
    const float* rw1  = (const float*)d_in[5];
    const float* rb1  = (const float*)d_in[6];
    const float* rw2  = (const float*)d_in[7];
    const float* rb2  = (const float*)d_in[8];
    const int*   eidx = (const int*)d_in[9];    // [2, NE]: rows then cols
    const int*   batch= (const int*)d_in[10];
    const int*   ddb  = (const int*)d_in[11];   // [2, NP]
    const int*   ecl  = (const int*)d_in[12];
    float* out = (float*)d_out;

    // ---- workspace layout (floats) ----
    // off(50048) | srows(NE) | dinv(50048) | bufA(6.4M) | bufB(6.4M)
    // temporal aliases:
    //   ebuf  (int NE)         -> bufA[0..0.8M)      (k_part .. k_bsort)
    //   cnt/btot/bbase         -> bufB[1.7M..1.86M)  (k_cnt .. k_bsort)
    //   xs    (fp16 [NN][64])  -> bufB[0..1.6M)      (k_bsort .. gath1)
    //   aggXh (fp16 [NN][64])  -> bufA[0..1.6M)      (gath1 .. gemm1)
    //   H1h   (fp16 [NN][128]) -> bufB[0..3.2M)      (gemm1 .. gath2)
    //   aggHh (fp16 [NN][128]) -> bufA[0..3.2M)      (gath2 .. gemm2)
    //   gsum  (f32 131072)     -> bufA[4.5M..4.63M)  (zeroed in gath1; gemm2 .. gemm_bat)
    //   w1t   (fp16 [128][64]) -> bufA[4.70M..)      (k_wconv .. gemm1)
    //   w2t   (fp16 [128][128])-> bufA[4.71M..)      (k_wconv .. gemm2)
    //   Aarr  (f32 4.19M)      -> bufA[0..4.19M)     (gemm_bat .. k_pair)
    //   Barr  (f32 4.19M)      -> bufB[0..4.19M)     (gemm_bat .. k_pair)
    int*   off   = (int*)d_ws;
    int*   srows = off + 50048;
    float* dinv  = (float*)(srows + NE);
    float* bufA  = dinv + 50048;
    float* bufB  = bufA + NN * EMB;

    int*    ebuf  = (int*)bufA;
    int*    cnt   = (int*)(bufB + 1700000);
    int*    btot  = cnt + NB * NCHUNK;
    int*    bbase = btot + 512;
    __half* xs    = (__half*)bufB;
    __half* aggXh = (__half*)bufA;
    __half* H1h   = (__half*)bufB;
    __half* aggHh = (__half*)bufA;
    float*  gsum  = bufA + 4500000;
    __half* w1t   = (__half*)(bufA + 4700000);
    __half* w2t   = (__half*)(bufA + 4710000);
    float*  Aarr  = bufA;
    float*  Barr  = bufB;

    const int* erow = eidx;
    const int* ecol = eidx + NE;

    // ---- weight fp16 transposes (independent; launch first) ----
    k_wconv<<<CDIV(INCH*128,256),256,0,stream>>>(c1w, w1t, INCH);
    k_wconv<<<CDIV(EMB*128,256),256,0,stream>>>(c2w, w2t, EMB);

    // ---- CSR build (bucketed, LDS-atomic only) + fused x->fp16 prescale ----
    k_cnt  <<<NCHUNK, 256, 0, stream>>>(ecol, cnt);
    k_bscan<<<NB,     512, 0, stream>>>(cnt, btot);
    k_btot <<<1,      512, 0, stream>>>(btot, bbase);
    k_part <<<NCHUNK, 256, 0, stream>>>(erow, ecol, cnt, bbase, ebuf);
    k_bsort<<<NB,     256, 0, stream>>>(ebuf, bbase, x, off, dinv, srows, xs);

    // ---- layer 1: aggX(fp16) = gather(xs) [+ zero gsum] ; H1'(fp16) = dinv*relu(aggX@W1+b1) ----
    k_gath_h<INCH,true><<<CDIV(NN,4),256,0,stream>>>(off, srows, dinv, xs, aggXh, gsum);
    gemm_mf<INCH,true,false><<<CDIV(NN,64),256,0,stream>>>(aggXh, w1t, c1b, dinv, nullptr, (float*)H1h, NN);

    // ---- layer 2: aggH(fp16) = gather(H1') ; MFMA gemm2 + fused mean-pool atomics ----
    k_gath_h<EMB,false><<<CDIV(NN,4),256,0,stream>>>(off, srows, dinv, H1h, aggHh, nullptr);
    gemm_mf<EMB,false,true><<<CDIV(NN,64),256,0,stream>>>(aggHh, w2t, c2b, nullptr, batch, gsum, NN);
    k_div<<<NG,128,0,stream>>>(gsum, batch);

    // ---- regressor: {A,B} = GE @ W1 halves for all 16 lines, then pair epilogue ----
    dim3 bgrid(NG/128, 2, 2*NCL);
    gemm_bat<<<bgrid,256,0,stream>>>(gsum, rw1, Aarr, Barr);
    k_pair<<<NP/4,256,0,stream>>>(Aarr, Barr, ddb, ecl, rb1, rw2, rb2, out);
}

// Round 13
// 171.857 us; speedup vs baseline: 1.1519x; 1.0375x over previous
//
#include <hip/hip_runtime.h>
#include <hip/hip_fp16.h>

#define NN 50000     // nodes
#define NE 800000    // edges
#define NG 1024      // graphs
#define NP 16384     // pairs
#define NCL 16       // cell lines
#define INCH 64
#define EMB 128
#define HID 256

#define NB 391       // node buckets of 128 (CDIV(NN,128))
#define NCHUNK 400   // edge chunks
#define EPB 2000     // edges per chunk (NE = 400*2000 exactly)

#define CDIV(a,b) (((a)+(b)-1)/(b))

typedef _Float16 f16x8 __attribute__((ext_vector_type(8)));
typedef float    f32x4 __attribute__((ext_vector_type(4)));

// ---------------- block exclusive scan (NW waves) ----------------
template<int NW>
__device__ __forceinline__ int block_excl_scan(int v, int t, int* incl_out) {
    int lane = t & 63, w = t >> 6;
    int s = v;
#pragma unroll
    for (int d = 1; d < 64; d <<= 1) {
        int u = __shfl_up(s, d, 64);
        if (lane >= d) s += u;
    }
    __shared__ int wsum[NW];
    if (lane == 63) wsum[w] = s;
    __syncthreads();
    int add = 0;
    for (int k = 0; k < w; ++k) add += wsum[k];
    *incl_out = s + add;
    return s + add - v;
}

// ---------------- Pass A: per-chunk bucket histogram ----------------
__global__ __launch_bounds__(256) void k_cnt(const int* __restrict__ cols,
                                             int* __restrict__ cnt) {
    __shared__ int hist[NB];
    int ch = blockIdx.x, t = threadIdx.x;
    for (int b = t; b < NB; b += 256) hist[b] = 0;
    __syncthreads();
    for (int e = ch * EPB + t; e < (ch + 1) * EPB; e += 256)
        atomicAdd(&hist[cols[e] >> 7], 1);
    __syncthreads();
    for (int b = t; b < NB; b += 256) cnt[b * NCHUNK + ch] = hist[b];
}

// ---------------- Pass B1: per-bucket scan over chunks ----------------
__global__ __launch_bounds__(512) void k_bscan(int* __restrict__ cnt,
                                               int* __restrict__ btot) {
    int b = blockIdx.x, t = threadIdx.x;
    int v = (t < NCHUNK) ? cnt[b * NCHUNK + t] : 0;
    int incl;
    int excl = block_excl_scan<8>(v, t, &incl);
    if (t < NCHUNK) cnt[b * NCHUNK + t] = excl;
    if (t == NCHUNK - 1) btot[b] = incl;
}

// ---------------- Pass B2: bucket-base scan ----------------
__global__ __launch_bounds__(512) void k_btot(const int* __restrict__ btot,
                                              int* __restrict__ bbase) {
    int t = threadIdx.x;
    int v = (t < NB) ? btot[t] : 0;
    int incl;
    int excl = block_excl_scan<8>(v, t, &incl);
    if (t < NB) bbase[t] = excl;
    if (t == NB - 1) bbase[NB] = incl;   // = NE
}

// ---------------- Pass C: partition edges (packed r<<7|c_local) ----------------
__global__ __launch_bounds__(256) void k_part(const int* __restrict__ rows,
                                              const int* __restrict__ cols,
                                              const int* __restrict__ cnt,
                                              const int* __restrict__ bbase,
                                              int* __restrict__ ebuf) {
    __shared__ int cur[NB];
    int ch = blockIdx.x, t = threadIdx.x;
    for (int b = t; b < NB; b += 256) cur[b] = bbase[b] + cnt[b * NCHUNK + ch];
    __syncthreads();
    for (int e = ch * EPB + t; e < (ch + 1) * EPB; e += 256) {
        int c = cols[e], r = rows[e];
        int pos = atomicAdd(&cur[c >> 7], 1);
        ebuf[pos] = (r << 7) | (c & 127);
    }
}

// ---------------- Pass D: per-bucket counting sort -> srows/off/dinv + x->fp16 ----------------
__global__ __launch_bounds__(256) void k_bsort(const int* __restrict__ ebuf,
                                               const int* __restrict__ bbase,
                                               const float* __restrict__ x,
                                               int* __restrict__ off,
                                               float* __restrict__ dinv,
                                               int* __restrict__ srows,
                                               __half* __restrict__ xs) {
    __shared__ int   ldeg[128];
    __shared__ int   lcur[128];
    __shared__ float ldinv[128];
    int b = blockIdx.x, t = threadIdx.x;
    int n0 = b << 7;
    int nloc = min(128, NN - n0);
    int beg = bbase[b], end = bbase[b + 1];
    if (t < 128) ldeg[t] = 0;
    __syncthreads();
    for (int i = beg + t; i < end; i += 256)
        atomicAdd(&ldeg[ebuf[i] & 127], 1);
    __syncthreads();
    int v = (t < nloc) ? ldeg[t] : 0;
    int incl;
    int excl = block_excl_scan<4>(v, t, &incl);
    if (t < nloc) {
        off[n0 + t]  = beg + excl + v;            // END offset convention
        float d = rsqrtf((float)(v + 1));         // +1 self-loop
        dinv[n0 + t] = d;
        ldinv[t] = d;
        lcur[t] = beg + excl;
    }
    __syncthreads();
    for (int i = beg + t; i < end; i += 256) {
        int e = ebuf[i];
        int pos = atomicAdd(&lcur[e & 127], 1);
        srows[pos] = e >> 7;
    }
    // fused: xs[row] = fp16(dinv[row] * x[row]) for this bucket's rows
    const float4* Xx = (const float4*)x;
#pragma unroll
    for (int i = 0; i < 8; ++i) {
        int f4 = t + i * 256;                     // 0..2047 (128 rows x 16 f4)
        int rloc = f4 >> 4, kq = f4 & 15;
        if (rloc < nloc) {
            float d = ldinv[rloc];
            float4 vv = Xx[(size_t)(n0 + rloc) * 16 + kq];
            __half2 h[2];
            h[0] = __floats2half2_rn(d * vv.x, d * vv.y);
            h[1] = __floats2half2_rn(d * vv.z, d * vv.w);
            ((float2*)xs)[(size_t)(n0 + rloc) * 16 + kq] = *(float2*)h;
        }
    }
}

// ---------------- weight convert: WT[n][k] = fp16(W[k][n]) (for gemm_mf) ----------------
__global__ __launch_bounds__(256) void k_wconv(const float* __restrict__ W,
                                               __half* __restrict__ WT, int K) {
    int i = blockIdx.x * 256 + threadIdx.x;   // over K*128, coalesced read
    if (i >= K * 128) return;
    int k = i >> 7, n = i & 127;
    WT[n * K + k] = __float2half(W[i]);
}

// ---------------- regressor weight convert: hi/lo fp16 transpose tables ----------------
// Whl layout: [pass(2)][z=c*2+part(32)][t(256)][k(128)] halfs; pass0=hi, pass1=lo.
// W1 source: rw1[c][k_in=part*128+k][t].
__global__ __launch_bounds__(256) void k_wconvb(const float* __restrict__ W1,
                                                __half* __restrict__ Whl) {
    int i = blockIdx.x * 256 + threadIdx.x;   // over 32*256*16 = 131072 chunk-units
    if (i >= 32 * 256 * 16) return;
    int ch = i & 15, tg = (i >> 4) & 255, z = i >> 12;
    int c = z >> 1, part = z & 1;
    f16x8 hi, lo;
#pragma unroll
    for (int j = 0; j < 8; ++j) {
        float v = W1[(size_t)c * 65536 + (size_t)(part * 128 + ch * 8 + j) * 256 + tg];
        _Float16 h = (_Float16)v;
        hi[j] = h;
        lo[j] = (_Float16)(v - (float)h);
    }
    size_t base = ((size_t)z * 256 + tg) * 16 + ch;   // in f16x8 units
    ((f16x8*)Whl)[base] = hi;
    ((f16x8*)Whl)[(size_t)32 * 256 * 16 + base] = lo;
}

// ---------------- gather on pre-scaled fp16 rows, fp16 output ----------------
template<int FEAT, bool ZB>
__global__ __launch_bounds__(256) void k_gath_h(const int* __restrict__ off,
                                                const int* __restrict__ srows,
                                                const float* __restrict__ dinv,
                                                const __half* __restrict__ SRC,
                                                __half* __restrict__ DST,
                                                float* __restrict__ zbuf) {
    if (ZB) {
        if (blockIdx.x < 512) zbuf[(blockIdx.x << 8) + threadIdx.x] = 0.f;
    }
    constexpr int NC = FEAT / 8;    // 16B chunks (8 halfs) per row
    constexpr int PL = NC / 8;      // chunks per lane (1 for 64, 2 for 128)
    int node = blockIdx.x * 4 + (threadIdx.x >> 6);
    int lane = threadIdx.x & 63;
    int slot = lane >> 3, q = lane & 7;
    if (node >= NN) return;
    int beg = node ? off[node - 1] : 0;
    int end = off[node];
    float di = dinv[node];
    const float4* S4 = (const float4*)SRC;

    float acc[PL][8];
#pragma unroll
    for (int i = 0; i < PL; ++i)
#pragma unroll
        for (int j = 0; j < 8; ++j) acc[i][j] = 0.f;

    if (slot == 0) {
#pragma unroll
        for (int i = 0; i < PL; ++i) {
            float4 raw = S4[node * NC + i * 8 + q];
            const __half2* h = (const __half2*)&raw;
#pragma unroll
            for (int j = 0; j < 4; ++j) {
                float2 f = __half22float2(h[j]);
                acc[i][2 * j + 0] = f.x;
                acc[i][2 * j + 1] = f.y;
            }
        }
    }
    for (int e = beg + slot; e < end; e += 8) {
        int r = srows[e];
#pragma unroll
        for (int i = 0; i < PL; ++i) {
            float4 raw = S4[r * NC + i * 8 + q];
            const __half2* h = (const __half2*)&raw;
#pragma unroll
            for (int j = 0; j < 4; ++j) {
                float2 f = __half22float2(h[j]);
                acc[i][2 * j + 0] += f.x;
                acc[i][2 * j + 1] += f.y;
            }
        }
    }
#pragma unroll
    for (int d = 8; d < 64; d <<= 1)
#pragma unroll
        for (int i = 0; i < PL; ++i)
#pragma unroll
            for (int j = 0; j < 8; ++j)
                acc[i][j] += __shfl_xor(acc[i][j], d, 64);

    if (lane < 8) {
        float4* D4 = (float4*)DST;   // 8 halfs per float4
#pragma unroll
        for (int i = 0; i < PL; ++i) {
            float4 pk;
            __half2* hp = (__half2*)&pk;
            hp[0] = __floats2half2_rn(di * acc[i][0], di * acc[i][1]);
            hp[1] = __floats2half2_rn(di * acc[i][2], di * acc[i][3]);
            hp[2] = __floats2half2_rn(di * acc[i][4], di * acc[i][5]);
            hp[3] = __floats2half2_rn(di * acc[i][6], di * acc[i][7]);
            D4[node * NC + i * 8 + lane] = pk;
        }
    }
}

// ---------------- MFMA node GEMM: Y[M,128] = X[M,K](fp16) @ W + bias, relu ----------------
template<int K, bool RS, bool POOL>
__global__ __launch_bounds__(256) void gemm_mf(const __half* __restrict__ X,
                                               const __half* __restrict__ WT,
                                               const float* __restrict__ bias,
                                               const float* __restrict__ rs,
                                               const int* __restrict__ batch,
                                               float* __restrict__ Y, int M) {
    constexpr int KP = K + 8;                 // padded fp16 row stride (16B-aligned)
    __shared__ __half Xs[64 * KP];
    __shared__ __half Ws[128 * KP];
    __shared__ int sb[64];
    const int t = threadIdx.x;
    const int row0 = blockIdx.x * 64;

    const float4* X8 = (const float4*)X;
#pragma unroll
    for (int i = t; i < 64 * (K / 8); i += 256) {
        int r = i / (K / 8), ch = i % (K / 8);
        float4 v = make_float4(0.f, 0.f, 0.f, 0.f);
        if (row0 + r < M) v = X8[(size_t)(row0 + r) * (K / 8) + ch];
        *(float4*)&Xs[r * KP + ch * 8] = v;
    }
    const float4* W8 = (const float4*)WT;
#pragma unroll
    for (int i = t; i < 128 * (K / 8); i += 256) {
        int n = i / (K / 8), ch = i % (K / 8);
        *(float4*)&Ws[n * KP + ch * 8] = W8[i];
    }
    if (POOL) {
        if (t < 64) sb[t] = (row0 + t < M) ? batch[row0 + t] : -1;
    }
    __syncthreads();

    const int w  = t >> 6;
    const int l  = t & 63;
    const int lm = l & 15, lg = l >> 4;

    f32x4 acc[8];
#pragma unroll
    for (int c = 0; c < 8; ++c) acc[c] = (f32x4){0.f, 0.f, 0.f, 0.f};

#pragma unroll
    for (int kk = 0; kk < K / 32; ++kk) {
        f16x8 a = *(const f16x8*)&Xs[(16 * w + lm) * KP + kk * 32 + lg * 8];
#pragma unroll
        for (int c = 0; c < 8; ++c) {
            f16x8 bf = *(const f16x8*)&Ws[(16 * c + lm) * KP + kk * 32 + lg * 8];
            acc[c] = __builtin_amdgcn_mfma_f32_16x16x32_f16(a, bf, acc[c], 0, 0, 0);
        }
    }

    float bcol[8];
#pragma unroll
    for (int c = 0; c < 8; ++c) bcol[c] = bias[16 * c + lm];

    if (POOL) {
#pragma unroll
        for (int c = 0; c < 8; ++c) {
            int rung = -1;
            float run = 0.f;
#pragma unroll
            for (int j = 0; j < 4; ++j) {
                int rr = 16 * w + 4 * lg + j;
                int g = (row0 + rr < M) ? sb[rr] : -1;
                if (g != rung) {
                    if (rung >= 0) atomicAdd(&Y[rung * 128 + 16 * c + lm], run);
                    run = 0.f;
                    rung = g;
                }
                if (g >= 0) run += fmaxf(acc[c][j] + bcol[c], 0.f);
            }
            if (rung >= 0) atomicAdd(&Y[rung * 128 + 16 * c + lm], run);
        }
        return;
    }

    __half* Yh = (__half*)Y;
#pragma unroll
    for (int j = 0; j < 4; ++j) {
        int r = row0 + 16 * w + 4 * lg + j;
        if (r < M) {
            float d = RS ? rs[r] : 1.f;
#pragma unroll
            for (int c = 0; c < 8; ++c) {
                float v = d * fmaxf(acc[c][j] + bcol[c], 0.f);
                Yh[(size_t)r * 128 + 16 * c + lm] = __float2half(v);
            }
        }
    }
}

// ---------------- normalize gsum -> mean, emit fp16 GE ----------------
__global__ __launch_bounds__(128) void k_div(const float* __restrict__ gsum,
                                             const int* __restrict__ batch,
                                             __half* __restrict__ geh) {
    int g = blockIdx.x;
    __shared__ float inv;
    if (threadIdx.x == 0) {
        int lo = 0, hi = NN;
        while (lo < hi) { int m = (lo + hi) >> 1; if (batch[m] < g) lo = m + 1; else hi = m; }
        int s = lo;
        lo = 0; hi = NN;
        while (lo < hi) { int m = (lo + hi) >> 1; if (batch[m] < g + 1) lo = m + 1; else hi = m; }
        float c = (float)(lo - s);
        inv = 1.f / fmaxf(c, 1.f);
    }
    __syncthreads();
    geh[g * 128 + threadIdx.x] = __float2half(gsum[g * 128 + threadIdx.x] * inv);
}

// ---------------- MFMA batched GEMM: {A,B}arr[c][g][t] = GE @ W1-half ----------------
// Block = 64 g-rows x 128 t-cols; grid (16, 2 panels, 32 z). Two passes (W hi, W lo)
// accumulate into the same f32 acc -> effectively f32-precision weights.
__global__ __launch_bounds__(256) void gemm_bat(const __half* __restrict__ GEh,
                                                const __half* __restrict__ Whl,
                                                float* __restrict__ Aarr,
                                                float* __restrict__ Barr) {
    constexpr int KP = 128 + 8;
    __shared__ __half Xs[64 * KP];
    __shared__ __half Ws[128 * KP];
    const int t = threadIdx.x;
    const int row0 = blockIdx.x * 64;
    const int y = blockIdx.y, z = blockIdx.z;

    // stage GE tile (64 x 128 fp16)
    const float4* X8 = (const float4*)GEh;
#pragma unroll
    for (int i = t; i < 64 * 16; i += 256) {
        int r = i >> 4, ch = i & 15;
        *(float4*)&Xs[r * KP + ch * 8] = X8[(size_t)(row0 + r) * 16 + ch];
    }

    const int w  = t >> 6;
    const int l  = t & 63;
    const int lm = l & 15, lg = l >> 4;

    f32x4 acc[8];
#pragma unroll
    for (int c = 0; c < 8; ++c) acc[c] = (f32x4){0.f, 0.f, 0.f, 0.f};

    const float4* W8 = (const float4*)Whl;
#pragma unroll
    for (int pass = 0; pass < 2; ++pass) {
        __syncthreads();   // Xs ready (pass 0) / Ws no longer read (pass 1)
        size_t wbase = ((size_t)pass * 32 + z) * 256 * 16;  // f16x8 units
#pragma unroll
        for (int i = t; i < 128 * 16; i += 256) {
            int n = i >> 4, ch = i & 15;
            *(float4*)&Ws[n * KP + ch * 8] = W8[wbase + (size_t)(y * 128 + n) * 16 + ch];
        }
        __syncthreads();
#pragma unroll
        for (int kk = 0; kk < 4; ++kk) {
            f16x8 a = *(const f16x8*)&Xs[(16 * w + lm) * KP + kk * 32 + lg * 8];
#pragma unroll
            for (int c = 0; c < 8; ++c) {
                f16x8 bf = *(const f16x8*)&Ws[(16 * c + lm) * KP + kk * 32 + lg * 8];
                acc[c] = __builtin_amdgcn_mfma_f32_16x16x32_f16(a, bf, acc[c], 0, 0, 0);
            }
        }
    }

    float* Obase = (z & 1) ? Barr : Aarr;
#pragma unroll
    for (int j = 0; j < 4; ++j) {
        int g = row0 + 16 * w + 4 * lg + j;
        size_t rb = ((size_t)(z >> 1) * NG + g) * HID + y * 128;
#pragma unroll
        for (int c = 0; c < 8; ++c)
            Obase[rb + 16 * c + lm] = acc[c][j];
    }
}

// ---------------- pair epilogue ----------------
__global__ __launch_bounds__(256) void k_pair(const float* __restrict__ Aarr,
                                              const float* __restrict__ Barr,
                                              const int* __restrict__ ddb,
                                              const int* __restrict__ ecl,
                                              const float* __restrict__ B1,
                                              const float* __restrict__ W2,
                                              const float* __restrict__ B2,
                                              float* __restrict__ out) {
    int p = blockIdx.x * 4 + (threadIdx.x >> 6);
    int lane = threadIdx.x & 63;
    int c = ecl[p];
    int a = ddb[p];
    int b = ddb[NP + p];
    const float4* rA = (const float4*)&Aarr[((size_t)c * NG + a) * HID];
    const float4* rB = (const float4*)&Barr[((size_t)c * NG + b) * HID];
    const float4* b1 = (const float4*)&B1[c * HID];
    const float4* w2 = (const float4*)&W2[c * HID];
    float4 va = rA[lane], vb = rB[lane], v1 = b1[lane], v2 = w2[lane];
    float hx = va.x + vb.x + v1.x;
    float hy = va.y + vb.y + v1.y;
    float hz = va.z + vb.z + v1.z;
    float hw = va.w + vb.w + v1.w;
    float s = 0.f;
    s = fmaf(hx > 0.f ? hx : 0.f, v2.x, s);
    s = fmaf(hy > 0.f ? hy : 0.f, v2.y, s);
    s = fmaf(hz > 0.f ? hz : 0.f, v2.z, s);
    s = fmaf(hw > 0.f ? hw : 0.f, v2.w, s);
    for (int o = 32; o; o >>= 1) s += __shfl_down(s, o, 64);
    if (lane == 0) out[p] = s + B2[c];
}

// ---------------- launch ----------------
extern "C" void kernel_launch(void* const* d_in, const int* in_sizes, int n_in,
                              void* d_out, int out_size, void* d_ws, size_t ws_size,
                              hipStream_t stream) {
    const float* x    = (const float*)d_in[0];
    const float* c1w  = (const float*)d_in[1];
    const float* c1b  = (const float*)d_in[2];
    const float* c2w  = (const float*)d_in[3];
    const float* c2b  = (const float*)d_in[4];
    const float* rw1  = (const float*)d_in[5];
    const float* rb1  = (const float*)d_in[6];
    const float* rw2  = (const float*)d_in[7];
    const float* rb2  = (const float*)d_in[8];
    const int*   eidx = (const int*)d_in[9];    // [2, NE]: rows then cols
    const int*   batch= (const int*)d_in[10];
    const int*   ddb  = (const int*)d_in[11];   // [2, NP]
    const int*   ecl  = (const int*)d_in[12];
    float* out = (float*)d_out;

    // ---- workspace layout (floats) ----
    // off(50048) | srows(NE) | dinv(50048) | bufA(6.4M) | bufB(6.4M)
    // temporal aliases:
    //   ebuf  (int NE)          -> bufA[0..0.8M)      (k_part .. k_bsort)
    //   cnt/btot/bbase          -> bufB[1.7M..1.86M)  (k_cnt .. k_bsort)
    //   xs    (fp16 [NN][64])   -> bufB[0..1.6M)      (k_bsort .. gath1)
    //   aggXh (fp16 [NN][64])   -> bufA[0..1.6M)      (gath1 .. gemm1)
    //   H1h   (fp16 [NN][128])  -> bufB[0..3.2M)      (gemm1 .. gath2)
    //   aggHh (fp16 [NN][128])  -> bufA[0..3.2M)      (gath2 .. gemm2)
    //   gsum  (f32 131072)      -> bufA[4.5M..4.63M)  (zeroed in gath1; gemm2 .. k_div)
    //   w1t   (fp16 [128][64])  -> bufA[4.70M..)      (k_wconv .. gemm1)
    //   w2t   (fp16 [128][128]) -> bufA[4.71M..)      (k_wconv .. gemm2)
    //   geh   (fp16 131072)     -> bufA[4.72M..4.79M) (k_div .. gemm_bat)
    //   Whl   (fp16 2x1.05M)    -> bufB[4.3M..5.35M)  (k_wconvb .. gemm_bat)
    //   Aarr  (f32 4.19M)       -> bufA[0..4.19M)     (gemm_bat .. k_pair)
    //   Barr  (f32 4.19M)       -> bufB[0..4.19M)     (gemm_bat .. k_pair)
    int*   off   = (int*)d_ws;
    int*   srows = off + 50048;
    float* dinv  = (float*)(srows + NE);
    float* bufA  = dinv + 50048;
    float* bufB  = bufA + NN * EMB;

    int*    ebuf  = (int*)bufA;
    int*    cnt   = (int*)(bufB + 1700000);
    int*    btot  = cnt + NB * NCHUNK;
    int*    bbase = btot + 512;
    __half* xs    = (__half*)bufB;
    __half* aggXh = (__half*)bufA;
    __half* H1h   = (__half*)bufB;
    __half* aggHh = (__half*)bufA;
    float*  gsum  = bufA + 4500000;
    __half* w1t   = (__half*)(bufA + 4700000);
    __half* w2t   = (__half*)(bufA + 4710000);
    __half* geh   = (__half*)(bufA + 4720000);
    __half* Whl   = (__half*)(bufB + 4300000);
    float*  Aarr  = bufA;
    float*  Barr  = bufB;

    const int* erow = eidx;
    const int* ecol = eidx + NE;

    // ---- weight fp16 conversions (independent; launch first) ----
    k_wconv<<<CDIV(INCH*128,256),256,0,stream>>>(c1w, w1t, INCH);
    k_wconv<<<CDIV(EMB*128,256),256,0,stream>>>(c2w, w2t, EMB);
    k_wconvb<<<CDIV(32*256*16,256),256,0,stream>>>(rw1, Whl);

    // ---- CSR build (bucketed, LDS-atomic only) + fused x->fp16 prescale ----
    k_cnt  <<<NCHUNK, 256, 0, stream>>>(ecol, cnt);
    k_bscan<<<NB,     512, 0, stream>>>(cnt, btot);
    k_btot <<<1,      512, 0, stream>>>(btot, bbase);
    k_part <<<NCHUNK, 256, 0, stream>>>(erow, ecol, cnt, bbase, ebuf);
    k_bsort<<<NB,     256, 0, stream>>>(ebuf, bbase, x, off, dinv, srows, xs);

    // ---- layer 1: aggX(fp16) = gather(xs) [+ zero gsum] ; H1'(fp16) = dinv*relu(aggX@W1+b1) ----
    k_gath_h<INCH,true><<<CDIV(NN,4),256,0,stream>>>(off, srows, dinv, xs, aggXh, gsum);
    gemm_mf<INCH,true,false><<<CDIV(NN,64),256,0,stream>>>(aggXh, w1t, c1b, dinv, nullptr, (float*)H1h, NN);

    // ---- layer 2: aggH(fp16) = gather(H1') ; MFMA gemm2 + fused mean-pool atomics ----
    k_gath_h<EMB,false><<<CDIV(NN,4),256,0,stream>>>(off, srows, dinv, H1h, aggHh, nullptr);
    gemm_mf<EMB,false,true><<<CDIV(NN,64),256,0,stream>>>(aggHh, w2t, c2b, nullptr, batch, gsum, NN);
    k_div<<<NG,128,0,stream>>>(gsum, batch, geh);

    // ---- regressor: MFMA {A,B} tables (hi+lo compensated), then pair epilogue ----
    dim3 bgrid(NG/64, 2, 2*NCL);
    gemm_bat<<<bgrid,256,0,stream>>>(geh, Whl, Aarr, Barr);
    k_pair<<<NP/4,256,0,stream>>>(Aarr, Barr, ddb, ecl, rb1, rw2, rb2, out);
}